// Round 3
// baseline (1412.066 us; speedup 1.0000x reference)
//
#include <hip/hip_runtime.h>
#include <hip/hip_bf16.h>

// ScatterEdges: out[n,48] = segsum(x*sw, src) - segsum(x*sw, dst)
// E = 1.6M, N = 50000, D = 48.
//
// R1: direct f32 atomics -> 1940us (atomic-op-rate bound, 16B RMW each).
// R2: full counting sort by node -> 917us; scatter of 4B items to 50000
//     random cursors cost 61B HBM writeback per item (WRITE_SIZE 197MB).
// R3: coarse multi-split into 391 buckets of 128 nodes (items written in
//     ~10-item contiguous runs per block-bucket), then one block per bucket
//     accumulates in a 24KB LDS tile with ds_add_f32 and stores its out
//     slice coalesced (no d_out memset needed -- every element written).

#define D_FEAT 48
#define RNODES 128                 // nodes per bucket (pow2; bucket = node>>7)
#define RSHIFT 7
#define NB_MAX 512                 // supports N <= 65536
#define EPB 2048                   // edges per block in hist/bin (256 thr x 8)

// ---- k1: per-bucket item histogram (LDS-privatized) ----
__global__ __launch_bounds__(256) void hist_kernel(
        const int* __restrict__ src, const int* __restrict__ dst,
        int* __restrict__ gcnt, int E, int NB) {
    __shared__ int lh[NB_MAX];
    for (int b = threadIdx.x; b < NB; b += 256) lh[b] = 0;
    __syncthreads();
    int base = blockIdx.x * EPB;
    #pragma unroll
    for (int i = 0; i < 8; ++i) {
        int e = base + i * 256 + threadIdx.x;
        if (e < E) {
            atomicAdd(&lh[src[e] >> RSHIFT], 1);
            atomicAdd(&lh[dst[e] >> RSHIFT], 1);
        }
    }
    __syncthreads();
    for (int b = threadIdx.x; b < NB; b += 256) {
        int c = lh[b];
        if (c) atomicAdd(&gcnt[b], c);
    }
}

// ---- k2: exclusive scan of gcnt -> goff, init gcur (single block) ----
__global__ __launch_bounds__(512) void scan_kernel(
        const int* __restrict__ gcnt, int* __restrict__ goff,
        int* __restrict__ gcur, int NB, int total) {
    __shared__ int s[NB_MAX];
    int t = threadIdx.x;
    int v = (t < NB) ? gcnt[t] : 0;
    s[t] = v;
    __syncthreads();
    for (int d = 1; d < 512; d <<= 1) {
        int a = (t >= d) ? s[t - d] : 0;
        __syncthreads();
        s[t] += a;
        __syncthreads();
    }
    if (t < NB) {
        int excl = s[t] - v;
        goff[t] = excl;
        gcur[t] = excl;
    }
    if (t == 0) goff[NB] = total;
}

// ---- k3: multi-split binning; item = (e<<8) | (side<<7) | (node&127) ----
__global__ __launch_bounds__(256) void bin_kernel(
        const int* __restrict__ src, const int* __restrict__ dst,
        int* __restrict__ gcur, int* __restrict__ items, int E, int NB) {
    __shared__ int lh[NB_MAX];     // phase A: local hist; phase C: local cursor
    __shared__ int lbase[NB_MAX];  // reserved global base per bucket
    for (int b = threadIdx.x; b < NB; b += 256) lh[b] = 0;
    __syncthreads();
    int base = blockIdx.x * EPB;
    #pragma unroll
    for (int i = 0; i < 8; ++i) {
        int e = base + i * 256 + threadIdx.x;
        if (e < E) {
            atomicAdd(&lh[src[e] >> RSHIFT], 1);
            atomicAdd(&lh[dst[e] >> RSHIFT], 1);
        }
    }
    __syncthreads();
    for (int b = threadIdx.x; b < NB; b += 256) {
        int c = lh[b];
        lbase[b] = c ? atomicAdd(&gcur[b], c) : 0;
        lh[b] = 0;  // becomes local cursor
    }
    __syncthreads();
    #pragma unroll
    for (int i = 0; i < 8; ++i) {
        int e = base + i * 256 + threadIdx.x;
        if (e < E) {
            int s0 = src[e];
            int b0 = s0 >> RSHIFT;
            int p0 = lbase[b0] + atomicAdd(&lh[b0], 1);
            items[p0] = (e << 8) | (s0 & (RNODES - 1));
            int d0 = dst[e];
            int b1 = d0 >> RSHIFT;
            int p1 = lbase[b1] + atomicAdd(&lh[b1], 1);
            items[p1] = (e << 8) | RNODES | (d0 & (RNODES - 1));
        }
    }
}

// ---- k4: per-bucket LDS accumulate + coalesced store ----
__global__ __launch_bounds__(1024) void gather_kernel(
        const float* __restrict__ x, const float* __restrict__ sw,
        const int* __restrict__ goff, const int* __restrict__ items,
        float* __restrict__ out, int N) {
    __shared__ float acc[RNODES * D_FEAT];  // 24 KB
    for (int i = threadIdx.x; i < RNODES * D_FEAT; i += 1024) acc[i] = 0.f;
    __syncthreads();

    int r = blockIdx.x;
    int lo = goff[r], hi = goff[r + 1];
    int wave = threadIdx.x >> 6;   // 0..15
    int lane = threadIdx.x & 63;

    if (lane < D_FEAT) {
        int i = lo + wave;
        for (; i + 48 < hi; i += 64) {  // 4 independent chains per wave
            int it0 = items[i], it1 = items[i + 16], it2 = items[i + 32], it3 = items[i + 48];
            int e0 = it0 >> 8, e1 = it1 >> 8, e2 = it2 >> 8, e3 = it3 >> 8;
            float w0 = sw[e0], w1 = sw[e1], w2 = sw[e2], w3 = sw[e3];
            w0 = (it0 & RNODES) ? -w0 : w0;
            w1 = (it1 & RNODES) ? -w1 : w1;
            w2 = (it2 & RNODES) ? -w2 : w2;
            w3 = (it3 & RNODES) ? -w3 : w3;
            float v0 = x[(size_t)e0 * D_FEAT + lane];
            float v1 = x[(size_t)e1 * D_FEAT + lane];
            float v2 = x[(size_t)e2 * D_FEAT + lane];
            float v3 = x[(size_t)e3 * D_FEAT + lane];
            atomicAdd(&acc[(it0 & (RNODES - 1)) * D_FEAT + lane], w0 * v0);
            atomicAdd(&acc[(it1 & (RNODES - 1)) * D_FEAT + lane], w1 * v1);
            atomicAdd(&acc[(it2 & (RNODES - 1)) * D_FEAT + lane], w2 * v2);
            atomicAdd(&acc[(it3 & (RNODES - 1)) * D_FEAT + lane], w3 * v3);
        }
        for (; i < hi; i += 16) {
            int it = items[i];
            int e = it >> 8;
            float w = sw[e];
            w = (it & RNODES) ? -w : w;
            float v = x[(size_t)e * D_FEAT + lane];
            atomicAdd(&acc[(it & (RNODES - 1)) * D_FEAT + lane], w * v);
        }
    }
    __syncthreads();

    int nbase = r * RNODES;
    int nn = min(RNODES, N - nbase);
    int tot = nn * D_FEAT;
    for (int idx = threadIdx.x; idx < tot; idx += 1024)
        out[(size_t)nbase * D_FEAT + idx] = acc[idx];
}

// ---- fallback: direct atomic scatter (correct, slow) ----
#define TPE 12
__global__ void atomic_fallback_kernel(const float4* __restrict__ x,
                                       const float* __restrict__ sw,
                                       const int* __restrict__ src,
                                       const int* __restrict__ dst,
                                       float* __restrict__ out, int n_edges) {
    int g = blockIdx.x * blockDim.x + threadIdx.x;
    int e = g / TPE;
    int q = g - e * TPE;
    if (e >= n_edges) return;
    float s = sw[e];
    float4 v = x[(size_t)e * TPE + q];
    v.x *= s; v.y *= s; v.z *= s; v.w *= s;
    int si = src[e], di = dst[e];
    float* po = out + (size_t)si * D_FEAT + q * 4;
    unsafeAtomicAdd(po + 0, v.x);
    unsafeAtomicAdd(po + 1, v.y);
    unsafeAtomicAdd(po + 2, v.z);
    unsafeAtomicAdd(po + 3, v.w);
    float* pd = out + (size_t)di * D_FEAT + q * 4;
    unsafeAtomicAdd(pd + 0, -v.x);
    unsafeAtomicAdd(pd + 1, -v.y);
    unsafeAtomicAdd(pd + 2, -v.z);
    unsafeAtomicAdd(pd + 3, -v.w);
}

extern "C" void kernel_launch(void* const* d_in, const int* in_sizes, int n_in,
                              void* d_out, int out_size, void* d_ws, size_t ws_size,
                              hipStream_t stream) {
    const float* x  = (const float*)d_in[0];
    const float* sw = (const float*)d_in[1];
    const int*   src = (const int*)d_in[2];
    const int*   dst = (const int*)d_in[3];
    float* out = (float*)d_out;

    int E = in_sizes[1];   // switch: [E]
    int N = in_sizes[4];   // species: [N]
    int NB = (N + RNODES - 1) / RNODES;

    // ws: gcnt[NB] | goff[NB+1] | gcur[NB] | items[2E]
    size_t need = ((size_t)NB * 3 + 1 + 2 * (size_t)E) * sizeof(int);

    if (NB > NB_MAX || ws_size < need) {
        hipMemsetAsync(d_out, 0, (size_t)out_size * sizeof(float), stream);
        long long total = (long long)E * TPE;
        int grid = (int)((total + 255) / 256);
        atomic_fallback_kernel<<<grid, 256, 0, stream>>>(
            (const float4*)x, sw, src, dst, out, E);
        return;
    }

    int* gcnt  = (int*)d_ws;
    int* goff  = gcnt + NB;
    int* gcur  = goff + NB + 1;
    int* items = gcur + NB;

    hipMemsetAsync(gcnt, 0, (size_t)NB * sizeof(int), stream);

    int eblk = (E + EPB - 1) / EPB;
    hist_kernel<<<eblk, 256, 0, stream>>>(src, dst, gcnt, E, NB);
    scan_kernel<<<1, 512, 0, stream>>>(gcnt, goff, gcur, NB, 2 * E);
    bin_kernel<<<eblk, 256, 0, stream>>>(src, dst, gcur, items, E, NB);
    gather_kernel<<<NB, 1024, 0, stream>>>(x, sw, goff, items, out, N);
}

// Round 4
// 1392.692 us; speedup vs baseline: 1.0139x; 1.0139x over previous
//
#include <hip/hip_runtime.h>
#include <hip/hip_bf16.h>

// ScatterEdges: out[n,48] = segsum(x*sw, src) - segsum(x*sw, dst)
// E = 1.6M, N = 50000, D = 48.
//
// R1: direct f32 atomics -> 1940us (atomic-op-rate bound, 16B RMW each).
// R2: full counting sort -> 917us (4B scattered item writes: 61B HBM/item).
// R3: 391x128-node buckets, 1024-thr gather -> 1412us. Gather was
//     latency-bound: 6256 waves, 50% occupancy, 4-deep MLP -> 557 GB/s.
// R4: 782x64-node buckets, 512-thr gather blocks (4/CU co-resident),
//     8-deep MLP (1.5KB in flight/wave), EPB 8192 for hist/bin.

#define D_FEAT 48
#define RNODES 64                  // nodes per bucket (bucket = node>>6)
#define RSHIFT 6
#define NB_MAX 1024                // supports N <= 65536
#define EPB 8192                   // edges per block in hist/bin (256 thr x 32)
#define DEPTH 8                    // gather unroll / MLP depth

// ---- k1: per-bucket item histogram (LDS-privatized) ----
__global__ __launch_bounds__(256) void hist_kernel(
        const int* __restrict__ src, const int* __restrict__ dst,
        int* __restrict__ gcnt, int E, int NB) {
    __shared__ int lh[NB_MAX];
    for (int b = threadIdx.x; b < NB; b += 256) lh[b] = 0;
    __syncthreads();
    int base = blockIdx.x * EPB;
    #pragma unroll
    for (int i = 0; i < 32; ++i) {
        int e = base + i * 256 + threadIdx.x;
        if (e < E) {
            atomicAdd(&lh[src[e] >> RSHIFT], 1);
            atomicAdd(&lh[dst[e] >> RSHIFT], 1);
        }
    }
    __syncthreads();
    for (int b = threadIdx.x; b < NB; b += 256) {
        int c = lh[b];
        if (c) atomicAdd(&gcnt[b], c);
    }
}

// ---- k2: exclusive scan of gcnt -> goff, init gcur (single block) ----
__global__ __launch_bounds__(1024) void scan_kernel(
        const int* __restrict__ gcnt, int* __restrict__ goff,
        int* __restrict__ gcur, int NB, int total) {
    __shared__ int s[NB_MAX];
    int t = threadIdx.x;
    int v = (t < NB) ? gcnt[t] : 0;
    s[t] = v;
    __syncthreads();
    for (int d = 1; d < 1024; d <<= 1) {
        int a = (t >= d) ? s[t - d] : 0;
        __syncthreads();
        s[t] += a;
        __syncthreads();
    }
    if (t < NB) {
        int excl = s[t] - v;
        goff[t] = excl;
        gcur[t] = excl;
    }
    if (t == 0) goff[NB] = total;
}

// ---- k3: multi-split binning; item = (e<<7) | (side<<6) | (node&63) ----
__global__ __launch_bounds__(256) void bin_kernel(
        const int* __restrict__ src, const int* __restrict__ dst,
        int* __restrict__ gcur, int* __restrict__ items, int E, int NB) {
    __shared__ int lh[NB_MAX];     // phase A: local hist; phase C: local cursor
    __shared__ int lbase[NB_MAX];  // reserved global base per bucket
    for (int b = threadIdx.x; b < NB; b += 256) lh[b] = 0;
    __syncthreads();
    int base = blockIdx.x * EPB;
    #pragma unroll
    for (int i = 0; i < 32; ++i) {
        int e = base + i * 256 + threadIdx.x;
        if (e < E) {
            atomicAdd(&lh[src[e] >> RSHIFT], 1);
            atomicAdd(&lh[dst[e] >> RSHIFT], 1);
        }
    }
    __syncthreads();
    for (int b = threadIdx.x; b < NB; b += 256) {
        int c = lh[b];
        lbase[b] = c ? atomicAdd(&gcur[b], c) : 0;
        lh[b] = 0;  // becomes local cursor
    }
    __syncthreads();
    #pragma unroll
    for (int i = 0; i < 32; ++i) {
        int e = base + i * 256 + threadIdx.x;
        if (e < E) {
            int s0 = src[e];
            int b0 = s0 >> RSHIFT;
            int p0 = lbase[b0] + atomicAdd(&lh[b0], 1);
            items[p0] = (e << 7) | (s0 & (RNODES - 1));
            int d0 = dst[e];
            int b1 = d0 >> RSHIFT;
            int p1 = lbase[b1] + atomicAdd(&lh[b1], 1);
            items[p1] = (e << 7) | RNODES | (d0 & (RNODES - 1));
        }
    }
}

// ---- k4: per-bucket LDS accumulate + coalesced store ----
__global__ __launch_bounds__(512, 6) void gather_kernel(
        const float* __restrict__ x, const float* __restrict__ sw,
        const int* __restrict__ goff, const int* __restrict__ items,
        float* __restrict__ out, int N) {
    __shared__ __align__(16) float acc[RNODES * D_FEAT];  // 12 KB
    for (int i = threadIdx.x; i < RNODES * D_FEAT; i += 512) acc[i] = 0.f;
    __syncthreads();

    int r = blockIdx.x;
    int lo = goff[r], hi = goff[r + 1];
    int wave = threadIdx.x >> 6;   // 0..7
    int lane = threadIdx.x & 63;

    // contiguous chunk per wave
    int cnt = hi - lo;
    int chunk = (cnt + 7) >> 3;
    int s0 = lo + wave * chunk;
    int s1 = min(s0 + chunk, hi);

    if (lane < D_FEAT) {
        int i = s0;
        for (; i + DEPTH <= s1; i += DEPTH) {
            int it[DEPTH];
            float w[DEPTH], v[DEPTH];
            #pragma unroll
            for (int k = 0; k < DEPTH; ++k) it[k] = items[i + k];
            #pragma unroll
            for (int k = 0; k < DEPTH; ++k) {
                int e = it[k] >> 7;
                w[k] = sw[e];
                v[k] = x[(size_t)e * D_FEAT + lane];
            }
            #pragma unroll
            for (int k = 0; k < DEPTH; ++k) {
                float ww = (it[k] & RNODES) ? -w[k] : w[k];
                atomicAdd(&acc[(it[k] & (RNODES - 1)) * D_FEAT + lane], ww * v[k]);
            }
        }
        for (; i < s1; ++i) {
            int it = items[i];
            int e = it >> 7;
            float w = sw[e];
            w = (it & RNODES) ? -w : w;
            atomicAdd(&acc[(it & (RNODES - 1)) * D_FEAT + lane],
                      w * x[(size_t)e * D_FEAT + lane]);
        }
    }
    __syncthreads();

    int nbase = r * RNODES;
    int nn = min(RNODES, N - nbase);
    int tot4 = nn * D_FEAT / 4;            // always divisible (48 % 4 == 0)
    float4* out4 = (float4*)(out + (size_t)nbase * D_FEAT);
    const float4* acc4 = (const float4*)acc;
    for (int idx = threadIdx.x; idx < tot4; idx += 512)
        out4[idx] = acc4[idx];
}

// ---- fallback: direct atomic scatter (correct, slow) ----
#define TPE 12
__global__ void atomic_fallback_kernel(const float4* __restrict__ x,
                                       const float* __restrict__ sw,
                                       const int* __restrict__ src,
                                       const int* __restrict__ dst,
                                       float* __restrict__ out, int n_edges) {
    int g = blockIdx.x * blockDim.x + threadIdx.x;
    int e = g / TPE;
    int q = g - e * TPE;
    if (e >= n_edges) return;
    float s = sw[e];
    float4 v = x[(size_t)e * TPE + q];
    v.x *= s; v.y *= s; v.z *= s; v.w *= s;
    int si = src[e], di = dst[e];
    float* po = out + (size_t)si * D_FEAT + q * 4;
    unsafeAtomicAdd(po + 0, v.x);
    unsafeAtomicAdd(po + 1, v.y);
    unsafeAtomicAdd(po + 2, v.z);
    unsafeAtomicAdd(po + 3, v.w);
    float* pd = out + (size_t)di * D_FEAT + q * 4;
    unsafeAtomicAdd(pd + 0, -v.x);
    unsafeAtomicAdd(pd + 1, -v.y);
    unsafeAtomicAdd(pd + 2, -v.z);
    unsafeAtomicAdd(pd + 3, -v.w);
}

extern "C" void kernel_launch(void* const* d_in, const int* in_sizes, int n_in,
                              void* d_out, int out_size, void* d_ws, size_t ws_size,
                              hipStream_t stream) {
    const float* x  = (const float*)d_in[0];
    const float* sw = (const float*)d_in[1];
    const int*   src = (const int*)d_in[2];
    const int*   dst = (const int*)d_in[3];
    float* out = (float*)d_out;

    int E = in_sizes[1];   // switch: [E]
    int N = in_sizes[4];   // species: [N]
    int NB = (N + RNODES - 1) / RNODES;

    // ws: gcnt[NB] | goff[NB+1] | gcur[NB] | items[2E]
    size_t need = ((size_t)NB * 3 + 1 + 2 * (size_t)E) * sizeof(int);

    if (NB > NB_MAX || ws_size < need) {
        hipMemsetAsync(d_out, 0, (size_t)out_size * sizeof(float), stream);
        long long total = (long long)E * TPE;
        int grid = (int)((total + 255) / 256);
        atomic_fallback_kernel<<<grid, 256, 0, stream>>>(
            (const float4*)x, sw, src, dst, out, E);
        return;
    }

    int* gcnt  = (int*)d_ws;
    int* goff  = gcnt + NB;
    int* gcur  = goff + NB + 1;
    int* items = gcur + NB;

    hipMemsetAsync(gcnt, 0, (size_t)NB * sizeof(int), stream);

    int eblk = (E + EPB - 1) / EPB;
    hist_kernel<<<eblk, 256, 0, stream>>>(src, dst, gcnt, E, NB);
    scan_kernel<<<1, 1024, 0, stream>>>(gcnt, goff, gcur, NB, 2 * E);
    bin_kernel<<<eblk, 256, 0, stream>>>(src, dst, gcur, items, E, NB);
    gather_kernel<<<NB, 512, 0, stream>>>(x, sw, goff, items, out, N);
}

// Round 5
// 622.616 us; speedup vs baseline: 2.2680x; 2.2368x over previous
//
#include <hip/hip_runtime.h>
#include <hip/hip_bf16.h>

// ScatterEdges: out[n,48] = segsum(x*sw, src) - segsum(x*sw, dst)
// E = 1.6M, N = 50000, D = 48.
//
// R1: direct f32 atomics -> 1940us (atomic-RMW-rate bound, 16B per f32 atomic).
// R2: full counting sort + wave-per-node gather -> 917us. Gather was fast
//     (>1.9TB/s, 50k waves); the 4B random-cursor scatter cost 61B HBM/item.
// R3/R4: bucket multi-split + bucket-LDS gather -> 1400us. Gather had only
//     6256 waves -> latency-bound at 537GB/s. Wave count, not MLP depth,
//     is the lever for random 192B row reads.
// R5: bucket multi-split (full-line item writes) + in-LDS per-bucket counting
//     sort to node order (emits per-node offsets) + R2-style wave-per-node
//     gather (50000 waves, 8-deep MLP, non-atomic coalesced stores).

#define D_FEAT 48
#define RNODES 64                  // nodes per bucket (bucket = node>>6)
#define RSHIFT 6
#define NB_MAX 1024                // supports N <= 65536
#define EPB 2048                   // edges per block in hist/bin (256 thr x 8)
#define DEPTH 8                    // gather MLP depth
#define SORT_CAP 12288             // max items/bucket staged in LDS (48KB);
                                   // mean 4096, std 64 -> 2.9x margin

// ---- k1: per-bucket item histogram (LDS-privatized) ----
__global__ __launch_bounds__(256) void hist_kernel(
        const int* __restrict__ src, const int* __restrict__ dst,
        int* __restrict__ gcnt, int E, int NB) {
    __shared__ int lh[NB_MAX];
    for (int b = threadIdx.x; b < NB; b += 256) lh[b] = 0;
    __syncthreads();
    int base = blockIdx.x * EPB;
    #pragma unroll
    for (int i = 0; i < 8; ++i) {
        int e = base + i * 256 + threadIdx.x;
        if (e < E) {
            atomicAdd(&lh[src[e] >> RSHIFT], 1);
            atomicAdd(&lh[dst[e] >> RSHIFT], 1);
        }
    }
    __syncthreads();
    for (int b = threadIdx.x; b < NB; b += 256) {
        int c = lh[b];
        if (c) atomicAdd(&gcnt[b], c);
    }
}

// ---- k2: exclusive scan of gcnt -> goff, init gcur; noff[N]=total ----
__global__ __launch_bounds__(1024) void scan_kernel(
        const int* __restrict__ gcnt, int* __restrict__ goff,
        int* __restrict__ gcur, int* __restrict__ noff,
        int NB, int N, int total) {
    __shared__ int s[NB_MAX];
    int t = threadIdx.x;
    int v = (t < NB) ? gcnt[t] : 0;
    s[t] = v;
    __syncthreads();
    for (int d = 1; d < 1024; d <<= 1) {
        int a = (t >= d) ? s[t - d] : 0;
        __syncthreads();
        s[t] += a;
        __syncthreads();
    }
    if (t < NB) {
        int excl = s[t] - v;
        goff[t] = excl;
        gcur[t] = excl;
    }
    if (t == 0) {
        goff[NB] = total;
        noff[N] = total;
    }
}

// ---- k3: multi-split binning; item = (e<<7) | (side<<6) | (node&63) ----
__global__ __launch_bounds__(256) void bin_kernel(
        const int* __restrict__ src, const int* __restrict__ dst,
        int* __restrict__ gcur, int* __restrict__ items, int E, int NB) {
    __shared__ int lh[NB_MAX];     // phase A: local hist; phase C: local cursor
    __shared__ int lbase[NB_MAX];  // reserved global base per bucket
    for (int b = threadIdx.x; b < NB; b += 256) lh[b] = 0;
    __syncthreads();
    int base = blockIdx.x * EPB;
    #pragma unroll
    for (int i = 0; i < 8; ++i) {
        int e = base + i * 256 + threadIdx.x;
        if (e < E) {
            atomicAdd(&lh[src[e] >> RSHIFT], 1);
            atomicAdd(&lh[dst[e] >> RSHIFT], 1);
        }
    }
    __syncthreads();
    for (int b = threadIdx.x; b < NB; b += 256) {
        int c = lh[b];
        lbase[b] = c ? atomicAdd(&gcur[b], c) : 0;
        lh[b] = 0;  // becomes local cursor
    }
    __syncthreads();
    #pragma unroll
    for (int i = 0; i < 8; ++i) {
        int e = base + i * 256 + threadIdx.x;
        if (e < E) {
            int s0 = src[e];
            int b0 = s0 >> RSHIFT;
            int p0 = lbase[b0] + atomicAdd(&lh[b0], 1);
            items[p0] = (e << 7) | (s0 & (RNODES - 1));
            int d0 = dst[e];
            int b1 = d0 >> RSHIFT;
            int p1 = lbase[b1] + atomicAdd(&lh[b1], 1);
            items[p1] = (e << 7) | RNODES | (d0 & (RNODES - 1));
        }
    }
}

// ---- k4: in-LDS counting sort of each bucket to node order (in place),
//          emits per-node offsets noff ----
__global__ __launch_bounds__(256) void sort_kernel(
        int* __restrict__ items, const int* __restrict__ goff,
        int* __restrict__ noff, int N) {
    __shared__ int sitems[SORT_CAP];           // 48 KB
    __shared__ int ccnt[RNODES];
    __shared__ int cbase[RNODES];
    int r = blockIdx.x;
    int lo = goff[r], hi = goff[r + 1];
    int cnt = hi - lo;                         // assumed <= SORT_CAP (2.9x margin)
    int t = threadIdx.x;

    if (t < RNODES) ccnt[t] = 0;
    __syncthreads();
    for (int i = t; i < cnt; i += 256) {
        int it = items[lo + i];
        sitems[i] = it;
        atomicAdd(&ccnt[it & (RNODES - 1)], 1);
    }
    __syncthreads();
    if (t < RNODES) {                          // wave 0: 64-lane inclusive scan
        int c = ccnt[t];
        int v = c;
        #pragma unroll
        for (int d = 1; d < 64; d <<= 1) {
            int a = __shfl_up(v, d);
            if (t >= d) v += a;
        }
        int excl = v - c;
        cbase[t] = excl;
        int n = r * RNODES + t;
        if (n < N) noff[n] = lo + excl;
        ccnt[t] = 0;                           // becomes cursor
    }
    __syncthreads();
    for (int i = t; i < cnt; i += 256) {
        int it = sitems[i];
        int loc = it & (RNODES - 1);
        int p = cbase[loc] + atomicAdd(&ccnt[loc], 1);
        items[lo + p] = it;
    }
}

// ---- k5: gather — one wave per node, lane = feature ----
__global__ __launch_bounds__(256) void gather_kernel(
        const float* __restrict__ x, const float* __restrict__ sw,
        const int* __restrict__ noff, const int* __restrict__ items,
        float* __restrict__ out, int N) {
    int n = (blockIdx.x * blockDim.x + threadIdx.x) >> 6;
    int lane = threadIdx.x & 63;
    if (n >= N) return;

    int lo = noff[n], hi = noff[n + 1];
    if (lane < D_FEAT) {
        float acc = 0.f;
        int i = lo;
        for (; i + DEPTH <= hi; i += DEPTH) {
            int it[DEPTH];
            float w[DEPTH], v[DEPTH];
            #pragma unroll
            for (int k = 0; k < DEPTH; ++k) it[k] = items[i + k];
            #pragma unroll
            for (int k = 0; k < DEPTH; ++k) {
                int e = it[k] >> 7;
                w[k] = sw[e];
                v[k] = x[(size_t)e * D_FEAT + lane];
            }
            #pragma unroll
            for (int k = 0; k < DEPTH; ++k) {
                float ww = (it[k] & RNODES) ? -w[k] : w[k];
                acc += ww * v[k];
            }
        }
        for (; i < hi; ++i) {
            int it = items[i];
            int e = it >> 7;
            float w = sw[e];
            w = (it & RNODES) ? -w : w;
            acc += w * x[(size_t)e * D_FEAT + lane];
        }
        out[(size_t)n * D_FEAT + lane] = acc;
    }
}

// ---- fallback: direct atomic scatter (correct, slow) ----
#define TPE 12
__global__ void atomic_fallback_kernel(const float4* __restrict__ x,
                                       const float* __restrict__ sw,
                                       const int* __restrict__ src,
                                       const int* __restrict__ dst,
                                       float* __restrict__ out, int n_edges) {
    int g = blockIdx.x * blockDim.x + threadIdx.x;
    int e = g / TPE;
    int q = g - e * TPE;
    if (e >= n_edges) return;
    float s = sw[e];
    float4 v = x[(size_t)e * TPE + q];
    v.x *= s; v.y *= s; v.z *= s; v.w *= s;
    int si = src[e], di = dst[e];
    float* po = out + (size_t)si * D_FEAT + q * 4;
    unsafeAtomicAdd(po + 0, v.x);
    unsafeAtomicAdd(po + 1, v.y);
    unsafeAtomicAdd(po + 2, v.z);
    unsafeAtomicAdd(po + 3, v.w);
    float* pd = out + (size_t)di * D_FEAT + q * 4;
    unsafeAtomicAdd(pd + 0, -v.x);
    unsafeAtomicAdd(pd + 1, -v.y);
    unsafeAtomicAdd(pd + 2, -v.z);
    unsafeAtomicAdd(pd + 3, -v.w);
}

extern "C" void kernel_launch(void* const* d_in, const int* in_sizes, int n_in,
                              void* d_out, int out_size, void* d_ws, size_t ws_size,
                              hipStream_t stream) {
    const float* x  = (const float*)d_in[0];
    const float* sw = (const float*)d_in[1];
    const int*   src = (const int*)d_in[2];
    const int*   dst = (const int*)d_in[3];
    float* out = (float*)d_out;

    int E = in_sizes[1];   // switch: [E]
    int N = in_sizes[4];   // species: [N]
    int NB = (N + RNODES - 1) / RNODES;

    // ws: gcnt[NB] | goff[NB+1] | gcur[NB] | noff[N+1] | items[2E]
    size_t need = ((size_t)NB * 3 + 1 + (size_t)N + 1 + 2 * (size_t)E) * sizeof(int);

    // expected max items/bucket ~4400 (mean 4096, binomial std 64); the LDS
    // sort caps at SORT_CAP. If inputs could exceed it, take the safe path.
    bool bucket_risk = ((long long)2 * E / (NB > 0 ? NB : 1)) * 2 > SORT_CAP;

    if (NB > NB_MAX || ws_size < need || bucket_risk) {
        hipMemsetAsync(d_out, 0, (size_t)out_size * sizeof(float), stream);
        long long total = (long long)E * TPE;
        int grid = (int)((total + 255) / 256);
        atomic_fallback_kernel<<<grid, 256, 0, stream>>>(
            (const float4*)x, sw, src, dst, out, E);
        return;
    }

    int* gcnt  = (int*)d_ws;
    int* goff  = gcnt + NB;
    int* gcur  = goff + NB + 1;
    int* noff  = gcur + NB;
    int* items = noff + N + 1;

    hipMemsetAsync(gcnt, 0, (size_t)NB * sizeof(int), stream);

    int eblk = (E + EPB - 1) / EPB;
    hist_kernel<<<eblk, 256, 0, stream>>>(src, dst, gcnt, E, NB);
    scan_kernel<<<1, 1024, 0, stream>>>(gcnt, goff, gcur, noff, NB, N, 2 * E);
    bin_kernel<<<eblk, 256, 0, stream>>>(src, dst, gcur, items, E, NB);
    sort_kernel<<<NB, 256, 0, stream>>>(items, goff, noff, N);

    int gblk = (int)(((long long)N * 64 + 255) / 256);
    gather_kernel<<<gblk, 256, 0, stream>>>(x, sw, noff, items, out, N);
}

// Round 6
// 581.510 us; speedup vs baseline: 2.4283x; 1.0707x over previous
//
#include <hip/hip_runtime.h>
#include <hip/hip_bf16.h>
#include <math.h>

// ScatterEdges: out[n,48] = segsum(x*sw, src) - segsum(x*sw, dst)
// E = 1.6M, N = 50000, D = 48.
//
// R1: direct f32 atomics -> 1940us (atomic-RMW-rate bound, 16B per f32 atomic).
// R2: full counting sort + wave-per-node gather -> 917us (4B random-cursor
//     scatter cost 61B HBM/item).
// R3/R4: bucket-LDS gather with 6k waves -> latency-bound, 537GB/s.
// R5: bucket multi-split + in-LDS bucket sort + wave-per-node gather (50k
//     waves) -> 622us total; gather 196us @ 3.0TB/s, ~126us other phases,
//     ~300us fixed harness overhead.
// R6: gather restructured to float4 lanes: 4 groups x 12 active lanes fetch
//     4 rows per load instr, 64-item chunks broadcast via __shfl (one
//     coalesced item load per 64), 16 rows (3KB) in flight per wave.
//     int4 loads in hist/bin; sort LDS 32KB.

#define D_FEAT 48
#define RNODES 64                  // nodes per bucket (bucket = node>>6)
#define RSHIFT 6
#define NB_MAX 1024                // supports N <= 65536
#define EPB 4096                   // edges per block in hist/bin (256 thr x 16)
#define SORT_CAP 8192              // max items/bucket in LDS sort (32KB)

// ---- k1: per-bucket item histogram (LDS-privatized, int4 loads) ----
__global__ __launch_bounds__(256) void hist_kernel(
        const int* __restrict__ src, const int* __restrict__ dst,
        int* __restrict__ gcnt, int E, int NB) {
    __shared__ int lh[NB_MAX];
    for (int b = threadIdx.x; b < NB; b += 256) lh[b] = 0;
    __syncthreads();
    int t = threadIdx.x;
    int base = blockIdx.x * EPB;
    #pragma unroll
    for (int i = 0; i < EPB / 1024; ++i) {
        int e = base + i * 1024 + t * 4;
        if (e + 3 < E) {
            int4 s4 = *(const int4*)(src + e);
            int4 d4 = *(const int4*)(dst + e);
            atomicAdd(&lh[s4.x >> RSHIFT], 1);
            atomicAdd(&lh[s4.y >> RSHIFT], 1);
            atomicAdd(&lh[s4.z >> RSHIFT], 1);
            atomicAdd(&lh[s4.w >> RSHIFT], 1);
            atomicAdd(&lh[d4.x >> RSHIFT], 1);
            atomicAdd(&lh[d4.y >> RSHIFT], 1);
            atomicAdd(&lh[d4.z >> RSHIFT], 1);
            atomicAdd(&lh[d4.w >> RSHIFT], 1);
        } else {
            for (int j = 0; j < 4; ++j) {
                int ee = e + j;
                if (ee < E) {
                    atomicAdd(&lh[src[ee] >> RSHIFT], 1);
                    atomicAdd(&lh[dst[ee] >> RSHIFT], 1);
                }
            }
        }
    }
    __syncthreads();
    for (int b = threadIdx.x; b < NB; b += 256) {
        int c = lh[b];
        if (c) atomicAdd(&gcnt[b], c);
    }
}

// ---- k2: exclusive scan of gcnt -> goff, init gcur; noff[N]=total ----
__global__ __launch_bounds__(1024) void scan_kernel(
        const int* __restrict__ gcnt, int* __restrict__ goff,
        int* __restrict__ gcur, int* __restrict__ noff,
        int NB, int N, int total) {
    __shared__ int s[NB_MAX];
    int t = threadIdx.x;
    int v = (t < NB) ? gcnt[t] : 0;
    s[t] = v;
    __syncthreads();
    for (int d = 1; d < 1024; d <<= 1) {
        int a = (t >= d) ? s[t - d] : 0;
        __syncthreads();
        s[t] += a;
        __syncthreads();
    }
    if (t < NB) {
        int excl = s[t] - v;
        goff[t] = excl;
        gcur[t] = excl;
    }
    if (t == 0) {
        goff[NB] = total;
        noff[N] = total;
    }
}

// ---- k3: multi-split binning; item = (e<<7) | (side<<6) | (node&63) ----
__device__ __forceinline__ void bin_place(int e, int node, int side,
                                          int* lh, const int* lbase,
                                          int* __restrict__ items) {
    int b = node >> RSHIFT;
    int p = lbase[b] + atomicAdd(&lh[b], 1);
    items[p] = (e << 7) | (side << 6) | (node & (RNODES - 1));
}

__global__ __launch_bounds__(256) void bin_kernel(
        const int* __restrict__ src, const int* __restrict__ dst,
        int* __restrict__ gcur, int* __restrict__ items, int E, int NB) {
    __shared__ int lh[NB_MAX];     // phase A: local hist; phase C: local cursor
    __shared__ int lbase[NB_MAX];  // reserved global base per bucket
    for (int b = threadIdx.x; b < NB; b += 256) lh[b] = 0;
    __syncthreads();
    int t = threadIdx.x;
    int base = blockIdx.x * EPB;
    #pragma unroll
    for (int i = 0; i < EPB / 1024; ++i) {
        int e = base + i * 1024 + t * 4;
        if (e + 3 < E) {
            int4 s4 = *(const int4*)(src + e);
            int4 d4 = *(const int4*)(dst + e);
            atomicAdd(&lh[s4.x >> RSHIFT], 1);
            atomicAdd(&lh[s4.y >> RSHIFT], 1);
            atomicAdd(&lh[s4.z >> RSHIFT], 1);
            atomicAdd(&lh[s4.w >> RSHIFT], 1);
            atomicAdd(&lh[d4.x >> RSHIFT], 1);
            atomicAdd(&lh[d4.y >> RSHIFT], 1);
            atomicAdd(&lh[d4.z >> RSHIFT], 1);
            atomicAdd(&lh[d4.w >> RSHIFT], 1);
        } else {
            for (int j = 0; j < 4; ++j) {
                int ee = e + j;
                if (ee < E) {
                    atomicAdd(&lh[src[ee] >> RSHIFT], 1);
                    atomicAdd(&lh[dst[ee] >> RSHIFT], 1);
                }
            }
        }
    }
    __syncthreads();
    for (int b = threadIdx.x; b < NB; b += 256) {
        int c = lh[b];
        lbase[b] = c ? atomicAdd(&gcur[b], c) : 0;
        lh[b] = 0;  // becomes local cursor
    }
    __syncthreads();
    #pragma unroll
    for (int i = 0; i < EPB / 1024; ++i) {
        int e = base + i * 1024 + t * 4;
        if (e + 3 < E) {
            int4 s4 = *(const int4*)(src + e);
            int4 d4 = *(const int4*)(dst + e);
            bin_place(e + 0, s4.x, 0, lh, lbase, items);
            bin_place(e + 1, s4.y, 0, lh, lbase, items);
            bin_place(e + 2, s4.z, 0, lh, lbase, items);
            bin_place(e + 3, s4.w, 0, lh, lbase, items);
            bin_place(e + 0, d4.x, 1, lh, lbase, items);
            bin_place(e + 1, d4.y, 1, lh, lbase, items);
            bin_place(e + 2, d4.z, 1, lh, lbase, items);
            bin_place(e + 3, d4.w, 1, lh, lbase, items);
        } else {
            for (int j = 0; j < 4; ++j) {
                int ee = e + j;
                if (ee < E) {
                    bin_place(ee, src[ee], 0, lh, lbase, items);
                    bin_place(ee, dst[ee], 1, lh, lbase, items);
                }
            }
        }
    }
}

// ---- k4: in-LDS counting sort of each bucket to node order (in place),
//          emits per-node offsets noff ----
__global__ __launch_bounds__(256) void sort_kernel(
        int* __restrict__ items, const int* __restrict__ goff,
        int* __restrict__ noff, int N) {
    __shared__ int sitems[SORT_CAP];           // 32 KB
    __shared__ int ccnt[RNODES];
    __shared__ int cbase[RNODES];
    int r = blockIdx.x;
    int lo = goff[r], hi = goff[r + 1];
    int cnt = hi - lo;                         // host-guarded <= SORT_CAP
    int t = threadIdx.x;

    if (t < RNODES) ccnt[t] = 0;
    __syncthreads();
    #pragma unroll 4
    for (int i = t; i < cnt; i += 256) {
        int it = items[lo + i];
        sitems[i] = it;
        atomicAdd(&ccnt[it & (RNODES - 1)], 1);
    }
    __syncthreads();
    if (t < RNODES) {                          // wave 0: 64-lane inclusive scan
        int c = ccnt[t];
        int v = c;
        #pragma unroll
        for (int d = 1; d < 64; d <<= 1) {
            int a = __shfl_up(v, d);
            if (t >= d) v += a;
        }
        int excl = v - c;
        cbase[t] = excl;
        int n = r * RNODES + t;
        if (n < N) noff[n] = lo + excl;
        ccnt[t] = 0;                           // becomes cursor
    }
    __syncthreads();
    #pragma unroll 4
    for (int i = t; i < cnt; i += 256) {
        int it = sitems[i];
        int loc = it & (RNODES - 1);
        int p = cbase[loc] + atomicAdd(&ccnt[loc], 1);
        items[lo + p] = it;
    }
}

// ---- k5: gather — one wave per node, 4 groups x 12 float4 lanes ----
__global__ __launch_bounds__(256, 4) void gather_kernel(
        const float4* __restrict__ x4, const float* __restrict__ sw,
        const int* __restrict__ noff, const int* __restrict__ items,
        float* __restrict__ out, int N) {
    int n = (blockIdx.x * blockDim.x + threadIdx.x) >> 6;
    int lane = threadIdx.x & 63;
    if (n >= N) return;

    int lo = noff[n], hi = noff[n + 1];
    int cnt = hi - lo;
    int grp = lane >> 4;        // 0..3: which item of a 4-item pack
    int sub = lane & 15;        // 0..15: float4 column index (active <12)

    float4 acc = make_float4(0.f, 0.f, 0.f, 0.f);

    for (int cb = 0; cb < cnt; cb += 64) {
        // one coalesced load covers 64 items; clamp for tail (cnt>0 here)
        int chunk = items[lo + min(cb + lane, cnt - 1)];
        int rem = cnt - cb;
        #pragma unroll
        for (int k = 0; k < 16; ++k) {
            int idx = k * 4 + grp;            // 0..63
            int it = __shfl(chunk, idx);
            int e = it >> 7;
            float w = (idx < rem) ? sw[e] : 0.f;
            w = (it & RNODES) ? -w : w;
            if (sub < 12) {
                float4 v = x4[(size_t)e * 12 + sub];
                acc.x += w * v.x;
                acc.y += w * v.y;
                acc.z += w * v.z;
                acc.w += w * v.w;
            }
        }
    }

    // fold groups: lanes 0..15 <- g0+g2+g1+g3
    acc.x += __shfl_down(acc.x, 32);
    acc.y += __shfl_down(acc.y, 32);
    acc.z += __shfl_down(acc.z, 32);
    acc.w += __shfl_down(acc.w, 32);
    acc.x += __shfl_down(acc.x, 16);
    acc.y += __shfl_down(acc.y, 16);
    acc.z += __shfl_down(acc.z, 16);
    acc.w += __shfl_down(acc.w, 16);

    if (lane < 12) {
        float4* orow = (float4*)(out + (size_t)n * D_FEAT);
        orow[lane] = acc;
    }
}

// ---- fallback: direct atomic scatter (correct, slow) ----
#define TPE 12
__global__ void atomic_fallback_kernel(const float4* __restrict__ x,
                                       const float* __restrict__ sw,
                                       const int* __restrict__ src,
                                       const int* __restrict__ dst,
                                       float* __restrict__ out, int n_edges) {
    int g = blockIdx.x * blockDim.x + threadIdx.x;
    int e = g / TPE;
    int q = g - e * TPE;
    if (e >= n_edges) return;
    float s = sw[e];
    float4 v = x[(size_t)e * TPE + q];
    v.x *= s; v.y *= s; v.z *= s; v.w *= s;
    int si = src[e], di = dst[e];
    float* po = out + (size_t)si * D_FEAT + q * 4;
    unsafeAtomicAdd(po + 0, v.x);
    unsafeAtomicAdd(po + 1, v.y);
    unsafeAtomicAdd(po + 2, v.z);
    unsafeAtomicAdd(po + 3, v.w);
    float* pd = out + (size_t)di * D_FEAT + q * 4;
    unsafeAtomicAdd(pd + 0, -v.x);
    unsafeAtomicAdd(pd + 1, -v.y);
    unsafeAtomicAdd(pd + 2, -v.z);
    unsafeAtomicAdd(pd + 3, -v.w);
}

extern "C" void kernel_launch(void* const* d_in, const int* in_sizes, int n_in,
                              void* d_out, int out_size, void* d_ws, size_t ws_size,
                              hipStream_t stream) {
    const float* x  = (const float*)d_in[0];
    const float* sw = (const float*)d_in[1];
    const int*   src = (const int*)d_in[2];
    const int*   dst = (const int*)d_in[3];
    float* out = (float*)d_out;

    int E = in_sizes[1];   // switch: [E]
    int N = in_sizes[4];   // species: [N]
    int NB = (N + RNODES - 1) / RNODES;

    // ws: gcnt[NB] | goff[NB+1] | gcur[NB] | noff[N+1] | items[2E]
    size_t need = ((size_t)NB * 3 + 1 + (size_t)N + 1 + 2 * (size_t)E) * sizeof(int);

    // LDS sort capacity guard: mean + 16 sigma must fit (uniform-random nodes)
    int mean = (NB > 0) ? (int)((long long)2 * E / NB) : 0;
    bool bucket_risk = mean + 16 * (int)sqrtf((float)(mean > 0 ? mean : 1)) > SORT_CAP;

    if (NB > NB_MAX || ws_size < need || bucket_risk) {
        hipMemsetAsync(d_out, 0, (size_t)out_size * sizeof(float), stream);
        long long total = (long long)E * TPE;
        int grid = (int)((total + 255) / 256);
        atomic_fallback_kernel<<<grid, 256, 0, stream>>>(
            (const float4*)x, sw, src, dst, out, E);
        return;
    }

    int* gcnt  = (int*)d_ws;
    int* goff  = gcnt + NB;
    int* gcur  = goff + NB + 1;
    int* noff  = gcur + NB;
    int* items = noff + N + 1;

    hipMemsetAsync(gcnt, 0, (size_t)NB * sizeof(int), stream);

    int eblk = (E + EPB - 1) / EPB;
    hist_kernel<<<eblk, 256, 0, stream>>>(src, dst, gcnt, E, NB);
    scan_kernel<<<1, 1024, 0, stream>>>(gcnt, goff, gcur, noff, NB, N, 2 * E);
    bin_kernel<<<eblk, 256, 0, stream>>>(src, dst, gcur, items, E, NB);
    sort_kernel<<<NB, 256, 0, stream>>>(items, goff, noff, N);

    int gblk = (int)(((long long)N * 64 + 255) / 256);
    gather_kernel<<<gblk, 256, 0, stream>>>((const float4*)x, sw, noff, items, out, N);
}